// Round 10
// baseline (901.984 us; speedup 1.0000x reference)
//
#include <hip/hip_runtime.h>

// ---------------------------------------------------------------------------
// LennardJones per-atom energy — bucketed two-pass (atomic-wall workaround).
//
// R9: 898 us (passA 481, passB ~410). passB was occupancy-starved: nb=245
// blocks = 1/CU, latency-bound on its record stream. R10: slice each bucket's
// records 8 ways -> nb*8 blocks, each accumulates its slice in LDS and writes
// an 8KB partial; reduce kernel sums 8 partials/atom. passA byte-identical.
// ws-guarded; fallbacks: R7 packed, then R1.
// ---------------------------------------------------------------------------

#define BUCKET_SHIFT 11
#define BUCKET_SIZE  2048
#define SLICES       8

__global__ void lj_cursor_init_kernel(int* __restrict__ cursor, int nb, int cap) {
    int i = blockIdx.x * blockDim.x + threadIdx.x;
    if (i < nb) cursor[i] = i * cap;
}

__global__ void lj_zero_kernel(float* __restrict__ out, long n) {
    long i = (long)blockIdx.x * blockDim.x + threadIdx.x;
    if (i < n) out[i] = 0.0f;
}

// packed[a] = {x, y, z, as_float(species)}
__global__ void lj_pack_kernel(const float* __restrict__ pos,
                               const int* __restrict__ species,
                               float4* __restrict__ packed, int n) {
    int i = blockIdx.x * blockDim.x + threadIdx.x;
    if (i < n) {
        float4 p;
        p.x = pos[3 * i];
        p.y = pos[3 * i + 1];
        p.z = pos[3 * i + 2];
        p.w = __int_as_float(species[i]);
        packed[i] = p;
    }
}

// Encode: round he's f32 bits to 12 mantissa bits, pack local id in low 11.
__device__ __forceinline__ unsigned int lj_encode(float he) {
    unsigned int u = __float_as_uint(he);
    return (u + 0x400u) & 0xFFFFF800u;
}

__global__ __launch_bounds__(256) void lj_passA_kernel(
    const float4* __restrict__ packed,
    const float* __restrict__ cell,
    const float* __restrict__ sigma_tab,
    const float* __restrict__ eps_tab,
    const float* __restrict__ shift_tab,
    const int* __restrict__ pair_i,
    const int* __restrict__ pair_j,
    const int* __restrict__ shifts,
    unsigned int* __restrict__ record_buf,
    int* __restrict__ cursor,
    int cap, int nb, int P)
{
    __shared__ float s_sig6[16];
    __shared__ float s_eps4[16];
    __shared__ float s_shift[16];
    __shared__ float s_cell[9];
    __shared__ int hist[256];
    __shared__ int basev[256];
    int t = threadIdx.x;
    if (t < 16) {
        float s = sigma_tab[t];
        float s3 = s * s * s;
        s_sig6[t] = s3 * s3;
        s_eps4[t] = 4.0f * eps_tab[t];
        s_shift[t] = shift_tab[t];
    }
    if (t < 9) s_cell[t] = cell[t];
    hist[t] = 0;
    __syncthreads();

    float c00 = s_cell[0], c01 = s_cell[1], c02 = s_cell[2];
    float c10 = s_cell[3], c11 = s_cell[4], c12 = s_cell[5];
    float c20 = s_cell[6], c21 = s_cell[7], c22 = s_cell[8];

    long base = (long)(blockIdx.x * (long)blockDim.x + t) * 4;

    int   ai[4], aj[4];
    float hev[4];
    int   sloti[4], slotj[4];
    bool  valid[4];

    if (base + 3 < P) {
        // Proven R7 load shape.
        int4 pi4 = *(const int4*)(pair_i + base);
        int4 pj4 = *(const int4*)(pair_j + base);
        int4 sA = *(const int4*)(shifts + base * 3);
        int4 sB = *(const int4*)(shifts + base * 3 + 4);
        int4 sC = *(const int4*)(shifts + base * 3 + 8);
        int pis[4] = {pi4.x, pi4.y, pi4.z, pi4.w};
        int pjs[4] = {pj4.x, pj4.y, pj4.z, pj4.w};
        int shv[12] = {sA.x, sA.y, sA.z, sA.w, sB.x, sB.y, sB.z, sB.w,
                       sC.x, sC.y, sC.z, sC.w};
#pragma unroll
        for (int k = 0; k < 4; ++k) {
            int i = pis[k], j = pjs[k];
            float fx = (float)shv[3 * k], fy = (float)shv[3 * k + 1], fz = (float)shv[3 * k + 2];
            float4 gi = packed[i];
            float4 gj = packed[j];
            float dx = gj.x - gi.x + fx * c00 + fy * c10 + fz * c20;
            float dy = gj.y - gi.y + fx * c01 + fy * c11 + fz * c21;
            float dz = gj.z - gi.z + fx * c02 + fy * c12 + fz * c22;
            float r2 = dx * dx + dy * dy + dz * dz;
            float r6 = r2 * r2 * r2;
            int idx = __float_as_int(gi.w) * 4 + __float_as_int(gj.w);
            float sr6 = s_sig6[idx] / r6;
            float sr12 = sr6 * sr6;
            hev[k] = 0.5f * (s_eps4[idx] * (sr12 - sr6) - s_shift[idx]);
            ai[k] = i; aj[k] = j; valid[k] = true;
        }
    } else {
#pragma unroll
        for (int k = 0; k < 4; ++k) {
            long p = base + k;
            valid[k] = (p < P);
            ai[k] = 0; aj[k] = 0; hev[k] = 0.0f;
            if (valid[k]) {
                int i = pair_i[p], j = pair_j[p];
                float fx = (float)shifts[3 * p], fy = (float)shifts[3 * p + 1], fz = (float)shifts[3 * p + 2];
                float4 gi = packed[i];
                float4 gj = packed[j];
                float dx = gj.x - gi.x + fx * c00 + fy * c10 + fz * c20;
                float dy = gj.y - gi.y + fx * c01 + fy * c11 + fz * c21;
                float dz = gj.z - gi.z + fx * c02 + fy * c12 + fz * c22;
                float r2 = dx * dx + dy * dy + dz * dz;
                float r6 = r2 * r2 * r2;
                int idx = __float_as_int(gi.w) * 4 + __float_as_int(gj.w);
                float sr6 = s_sig6[idx] / r6;
                float sr12 = sr6 * sr6;
                hev[k] = 0.5f * (s_eps4[idx] * (sr12 - sr6) - s_shift[idx]);
                ai[k] = i; aj[k] = j;
            }
        }
    }

    // Histogram phase (LDS atomics; slot = position within this block's chunk).
#pragma unroll
    for (int k = 0; k < 4; ++k) {
        if (valid[k]) {
            sloti[k] = atomicAdd(&hist[ai[k] >> BUCKET_SHIFT], 1);
            slotj[k] = atomicAdd(&hist[aj[k] >> BUCKET_SHIFT], 1);
        } else {
            sloti[k] = 0; slotj[k] = 0;
        }
    }
    __syncthreads();

    // Reserve per-bucket space: ONE global atomic per touched bucket per block.
    if (t < nb) {
        int h = hist[t];
        basev[t] = (h > 0) ? atomicAdd(&cursor[t], h) : 0;
    }
    __syncthreads();

    // Write records.
#pragma unroll
    for (int k = 0; k < 4; ++k) {
        if (valid[k]) {
            unsigned int u = lj_encode(hev[k]);
            int bi = ai[k] >> BUCKET_SHIFT;
            int wi = basev[bi] + sloti[k];
            if (wi < (bi + 1) * cap)
                record_buf[wi] = u | (unsigned int)(ai[k] & (BUCKET_SIZE - 1));
            int bj = aj[k] >> BUCKET_SHIFT;
            int wj = basev[bj] + slotj[k];
            if (wj < (bj + 1) * cap)
                record_buf[wj] = u | (unsigned int)(aj[k] & (BUCKET_SIZE - 1));
        }
    }
}

// One block per (bucket, slice). Accumulate slice's records into LDS, write
// an 8KB partial to ws.
__global__ __launch_bounds__(256) void lj_passB_kernel(
    const unsigned int* __restrict__ record_buf,
    const int* __restrict__ cursor,
    float* __restrict__ partial,
    int cap)
{
    __shared__ float e[BUCKET_SIZE];
    int blk = blockIdx.x;
    int b = blk >> 3;            // bucket
    int s = blk & (SLICES - 1);  // slice
    int t = threadIdx.x;
#pragma unroll
    for (int k = 0; k < 8; ++k) e[t + 256 * k] = 0.0f;
    __syncthreads();

    int begin = b * cap;
    int count = cursor[b] - begin;
    if (count > cap) count = cap;

    int ngroups = (count + 7) >> 3;                 // groups of 8 records
    int gps = (ngroups + SLICES - 1) / SLICES;      // groups per slice
    int g0 = s * gps;
    int g1 = g0 + gps;
    if (g1 > ngroups) g1 = ngroups;

    for (int g = g0 + t; g < g1; g += 256) {
        int r0 = g * 8;
        const unsigned int* rp = record_buf + begin + r0;
        if (r0 + 8 <= count) {
            int4 a = *(const int4*)(rp);
            int4 c = *(const int4*)(rp + 4);
            unsigned int w0 = (unsigned int)a.x, w1 = (unsigned int)a.y;
            unsigned int w2 = (unsigned int)a.z, w3 = (unsigned int)a.w;
            unsigned int w4 = (unsigned int)c.x, w5 = (unsigned int)c.y;
            unsigned int w6 = (unsigned int)c.z, w7 = (unsigned int)c.w;
            atomicAdd(&e[w0 & 2047u], __uint_as_float(w0 & 0xFFFFF800u));
            atomicAdd(&e[w1 & 2047u], __uint_as_float(w1 & 0xFFFFF800u));
            atomicAdd(&e[w2 & 2047u], __uint_as_float(w2 & 0xFFFFF800u));
            atomicAdd(&e[w3 & 2047u], __uint_as_float(w3 & 0xFFFFF800u));
            atomicAdd(&e[w4 & 2047u], __uint_as_float(w4 & 0xFFFFF800u));
            atomicAdd(&e[w5 & 2047u], __uint_as_float(w5 & 0xFFFFF800u));
            atomicAdd(&e[w6 & 2047u], __uint_as_float(w6 & 0xFFFFF800u));
            atomicAdd(&e[w7 & 2047u], __uint_as_float(w7 & 0xFFFFF800u));
        } else {
            for (int r = r0; r < count; ++r) {
                unsigned int w = record_buf[begin + r];
                atomicAdd(&e[w & 2047u], __uint_as_float(w & 0xFFFFF800u));
            }
        }
    }
    __syncthreads();

    float* pb = partial + (long)blk * BUCKET_SIZE;
#pragma unroll
    for (int k = 0; k < 8; ++k) pb[t + 256 * k] = e[t + 256 * k];
}

// energy[i] = sum of SLICES partials for i's bucket.
__global__ void lj_reduce_kernel(const float* __restrict__ partial,
                                 float* __restrict__ energy, int N) {
    int i = blockIdx.x * blockDim.x + threadIdx.x;
    if (i < N) {
        int b = i >> BUCKET_SHIFT;
        int l = i & (BUCKET_SIZE - 1);
        const float* pb = partial + ((long)b * SLICES) * BUCKET_SIZE + l;
        float s = 0.0f;
#pragma unroll
        for (int k = 0; k < SLICES; ++k) s += pb[(long)k * BUCKET_SIZE];
        energy[i] = s;
    }
}

// ------------------- R7 packed fallback (proven, 1561 us) -------------------
__device__ __forceinline__ void lj_one_pair_packed(
    int i, int j, float fx, float fy, float fz,
    const float4* __restrict__ packed,
    const float* s_sig6, const float* s_eps4, const float* s_shift,
    float c00, float c01, float c02,
    float c10, float c11, float c12,
    float c20, float c21, float c22,
    float* __restrict__ energy)
{
    float4 gi = packed[i];
    float4 gj = packed[j];
    float dx = gj.x - gi.x + fx * c00 + fy * c10 + fz * c20;
    float dy = gj.y - gi.y + fx * c01 + fy * c11 + fz * c21;
    float dz = gj.z - gi.z + fx * c02 + fy * c12 + fz * c22;
    float r2 = dx * dx + dy * dy + dz * dz;
    float r6 = r2 * r2 * r2;
    int idx = __float_as_int(gi.w) * 4 + __float_as_int(gj.w);
    float sr6 = s_sig6[idx] / r6;
    float sr12 = sr6 * sr6;
    float he = 0.5f * (s_eps4[idx] * (sr12 - sr6) - s_shift[idx]);
    atomicAdd(energy + i, he);
    atomicAdd(energy + j, he);
}

__global__ __launch_bounds__(256) void lj_pairs_packed_kernel(
    const float4* __restrict__ packed,
    const float* __restrict__ cell,
    const float* __restrict__ sigma_tab,
    const float* __restrict__ eps_tab,
    const float* __restrict__ shift_tab,
    const int* __restrict__ pair_i,
    const int* __restrict__ pair_j,
    const int* __restrict__ shifts,
    float* __restrict__ energy,
    int P)
{
    __shared__ float s_sig6[16];
    __shared__ float s_eps4[16];
    __shared__ float s_shift[16];
    __shared__ float s_cell[9];
    int t = threadIdx.x;
    if (t < 16) {
        float s = sigma_tab[t];
        float s3 = s * s * s;
        s_sig6[t] = s3 * s3;
        s_eps4[t] = 4.0f * eps_tab[t];
        s_shift[t] = shift_tab[t];
    }
    if (t < 9) s_cell[t] = cell[t];
    __syncthreads();

    float c00 = s_cell[0], c01 = s_cell[1], c02 = s_cell[2];
    float c10 = s_cell[3], c11 = s_cell[4], c12 = s_cell[5];
    float c20 = s_cell[6], c21 = s_cell[7], c22 = s_cell[8];

    long base = (long)(blockIdx.x * (long)blockDim.x + t) * 4;
    if (base + 3 < P) {
        int4 pi4 = *(const int4*)(pair_i + base);
        int4 pj4 = *(const int4*)(pair_j + base);
        int4 sA = *(const int4*)(shifts + base * 3);
        int4 sB = *(const int4*)(shifts + base * 3 + 4);
        int4 sC = *(const int4*)(shifts + base * 3 + 8);
        int pis[4] = {pi4.x, pi4.y, pi4.z, pi4.w};
        int pjs[4] = {pj4.x, pj4.y, pj4.z, pj4.w};
        int shv[12] = {sA.x, sA.y, sA.z, sA.w, sB.x, sB.y, sB.z, sB.w,
                       sC.x, sC.y, sC.z, sC.w};
#pragma unroll
        for (int k = 0; k < 4; ++k) {
            lj_one_pair_packed(pis[k], pjs[k],
                        (float)shv[3 * k], (float)shv[3 * k + 1], (float)shv[3 * k + 2],
                        packed, s_sig6, s_eps4, s_shift,
                        c00, c01, c02, c10, c11, c12, c20, c21, c22, energy);
        }
    } else {
        for (long p = base; p < P; ++p) {
            lj_one_pair_packed(pair_i[p], pair_j[p],
                        (float)shifts[3 * p], (float)shifts[3 * p + 1], (float)shifts[3 * p + 2],
                        packed, s_sig6, s_eps4, s_shift,
                        c00, c01, c02, c10, c11, c12, c20, c21, c22, energy);
        }
    }
}

// --------------------- R1 fallback (no workspace at all) --------------------
__device__ __forceinline__ void lj_one_pair(
    int i, int j, float fx, float fy, float fz,
    const float* __restrict__ pos,
    const int* __restrict__ species,
    const float* s_sig6, const float* s_eps4, const float* s_shift,
    float c00, float c01, float c02,
    float c10, float c11, float c12,
    float c20, float c21, float c22,
    float* __restrict__ energy)
{
    float dx = pos[3 * j]     - pos[3 * i]     + fx * c00 + fy * c10 + fz * c20;
    float dy = pos[3 * j + 1] - pos[3 * i + 1] + fx * c01 + fy * c11 + fz * c21;
    float dz = pos[3 * j + 2] - pos[3 * i + 2] + fx * c02 + fy * c12 + fz * c22;
    float r2 = dx * dx + dy * dy + dz * dz;
    float r6 = r2 * r2 * r2;
    int idx = species[i] * 4 + species[j];
    float sr6 = s_sig6[idx] / r6;
    float sr12 = sr6 * sr6;
    float he = 0.5f * (s_eps4[idx] * (sr12 - sr6) - s_shift[idx]);
    atomicAdd(energy + i, he);
    atomicAdd(energy + j, he);
}

__global__ __launch_bounds__(256) void lj_pairs_kernel(
    const float* __restrict__ pos,
    const float* __restrict__ cell,
    const float* __restrict__ sigma_tab,
    const float* __restrict__ eps_tab,
    const float* __restrict__ shift_tab,
    const int* __restrict__ species,
    const int* __restrict__ pair_i,
    const int* __restrict__ pair_j,
    const int* __restrict__ shifts,
    float* __restrict__ energy,
    int P)
{
    __shared__ float s_sig6[16];
    __shared__ float s_eps4[16];
    __shared__ float s_shift[16];
    __shared__ float s_cell[9];
    int t = threadIdx.x;
    if (t < 16) {
        float s = sigma_tab[t];
        float s3 = s * s * s;
        s_sig6[t] = s3 * s3;
        s_eps4[t] = 4.0f * eps_tab[t];
        s_shift[t] = shift_tab[t];
    }
    if (t < 9) s_cell[t] = cell[t];
    __syncthreads();

    float c00 = s_cell[0], c01 = s_cell[1], c02 = s_cell[2];
    float c10 = s_cell[3], c11 = s_cell[4], c12 = s_cell[5];
    float c20 = s_cell[6], c21 = s_cell[7], c22 = s_cell[8];

    long base = (long)(blockIdx.x * (long)blockDim.x + t) * 4;
    if (base + 3 < P) {
        int4 pi4 = *(const int4*)(pair_i + base);
        int4 pj4 = *(const int4*)(pair_j + base);
        int4 sA = *(const int4*)(shifts + base * 3);
        int4 sB = *(const int4*)(shifts + base * 3 + 4);
        int4 sC = *(const int4*)(shifts + base * 3 + 8);
        int pis[4] = {pi4.x, pi4.y, pi4.z, pi4.w};
        int pjs[4] = {pj4.x, pj4.y, pj4.z, pj4.w};
        int shv[12] = {sA.x, sA.y, sA.z, sA.w, sB.x, sB.y, sB.z, sB.w,
                       sC.x, sC.y, sC.z, sC.w};
#pragma unroll
        for (int k = 0; k < 4; ++k) {
            lj_one_pair(pis[k], pjs[k],
                        (float)shv[3 * k], (float)shv[3 * k + 1], (float)shv[3 * k + 2],
                        pos, species, s_sig6, s_eps4, s_shift,
                        c00, c01, c02, c10, c11, c12, c20, c21, c22, energy);
        }
    } else {
        for (long p = base; p < P; ++p) {
            lj_one_pair(pair_i[p], pair_j[p],
                        (float)shifts[3 * p], (float)shifts[3 * p + 1], (float)shifts[3 * p + 2],
                        pos, species, s_sig6, s_eps4, s_shift,
                        c00, c01, c02, c10, c11, c12, c20, c21, c22, energy);
        }
    }
}

extern "C" void kernel_launch(void* const* d_in, const int* in_sizes, int n_in,
                              void* d_out, int out_size, void* d_ws, size_t ws_size,
                              hipStream_t stream) {
    const float* positions = (const float*)d_in[0];
    const float* cell      = (const float*)d_in[1];
    const float* sigma_tab = (const float*)d_in[2];
    const float* eps_tab   = (const float*)d_in[3];
    const float* shift_tab = (const float*)d_in[4];
    const int*   species   = (const int*)d_in[5];
    const int*   pair_i    = (const int*)d_in[6];
    const int*   pair_j    = (const int*)d_in[7];
    const int*   shifts    = (const int*)d_in[8];
    float* energy = (float*)d_out;

    const int N = out_size;
    const int P = in_sizes[6];

    const int threads = 256;
    const int ablocks = (N + threads - 1) / threads;
    const int pblocks4 = (int)((((long)P + 3) / 4 + threads - 1) / threads);

    // Bucket path sizing.
    const int nb = (N + BUCKET_SIZE - 1) / BUCKET_SIZE;          // buckets
    long avg = (2L * P) / (nb > 0 ? nb : 1);
    long capl = (avg + avg / 50 + 512 + 1023) & ~1023L;          // ~1.02x + slack, mult of 1024
    const int cap = (int)capl;
    // ws layout: [records nb*cap u32][packed N float4][cursor nb i32][partial nb*SLICES*2048 f32]
    const size_t rec_bytes  = (size_t)nb * (size_t)cap * 4u;
    const size_t pack_bytes = (size_t)N * 16u;
    const size_t cur_bytes  = (size_t)nb * 4u;
    const size_t part_bytes = (size_t)nb * SLICES * BUCKET_SIZE * 4u;
    const size_t need_bucket = rec_bytes + pack_bytes + cur_bytes + part_bytes;
    const size_t need_pack   = pack_bytes;

    const bool has_ws = (d_ws != nullptr);
    const bool sane = (nb > 0) && (nb <= 256) && ((long)nb * cap < 2000000000L);
    const bool use_bucket = has_ws && sane && (ws_size >= need_bucket);
    const bool use_pack   = has_ws && !use_bucket && (ws_size >= need_pack);

    if (use_bucket) {
        unsigned int* record_buf = (unsigned int*)d_ws;
        float4* packed = (float4*)((char*)d_ws + rec_bytes);
        int* cursor = (int*)((char*)d_ws + rec_bytes + pack_bytes);
        float* partial = (float*)((char*)d_ws + rec_bytes + pack_bytes + cur_bytes);

        lj_cursor_init_kernel<<<1, 256, 0, stream>>>(cursor, nb, cap);
        lj_pack_kernel<<<ablocks, threads, 0, stream>>>(positions, species, packed, N);
        lj_passA_kernel<<<pblocks4, threads, 0, stream>>>(
            packed, cell, sigma_tab, eps_tab, shift_tab,
            pair_i, pair_j, shifts, record_buf, cursor, cap, nb, P);
        lj_passB_kernel<<<nb * SLICES, threads, 0, stream>>>(record_buf, cursor, partial, cap);
        lj_reduce_kernel<<<ablocks, threads, 0, stream>>>(partial, energy, N);
    } else if (use_pack) {
        float4* packed = (float4*)d_ws;
        lj_zero_kernel<<<ablocks, threads, 0, stream>>>(energy, N);
        lj_pack_kernel<<<ablocks, threads, 0, stream>>>(positions, species, packed, N);
        lj_pairs_packed_kernel<<<pblocks4, threads, 0, stream>>>(
            packed, cell, sigma_tab, eps_tab, shift_tab,
            pair_i, pair_j, shifts, energy, P);
    } else {
        lj_zero_kernel<<<ablocks, threads, 0, stream>>>(energy, N);
        lj_pairs_kernel<<<pblocks4, threads, 0, stream>>>(
            positions, cell, sigma_tab, eps_tab, shift_tab, species,
            pair_i, pair_j, shifts, energy, P);
    }
}

// Round 11
// 823.696 us; speedup vs baseline: 1.0950x; 1.0950x over previous
//
#include <hip/hip_runtime.h>

// ---------------------------------------------------------------------------
// LennardJones per-atom energy — bucketed two-pass.
//
// R11: passA gather working set shrunk 16B -> 8B per atom (u64 = 3 x u16
// fixed-point coords [0,32)/2048 + species). 4MB table fits each XCD's 4MB L2
// -> gathers become L2 hits instead of 50% L3 misses. Everything else
// (records, passB slices, reduce, fallbacks) identical to R10.
// ws-guarded; fallbacks: R7 packed float4, then R1.
// ---------------------------------------------------------------------------

#define BUCKET_SHIFT 11
#define BUCKET_SIZE  2048
#define SLICES       8
#define QSCALE       2048.0f
#define QINV         (1.0f / 2048.0f)

__global__ void lj_cursor_init_kernel(int* __restrict__ cursor, int nb, int cap) {
    int i = blockIdx.x * blockDim.x + threadIdx.x;
    if (i < nb) cursor[i] = i * cap;
}

__global__ void lj_zero_kernel(float* __restrict__ out, long n) {
    long i = (long)blockIdx.x * blockDim.x + threadIdx.x;
    if (i < n) out[i] = 0.0f;
}

// tab8[a] = x_u16 | y_u16<<16 | z_u16<<32 | species<<48  (coords * 2048)
__global__ void lj_pack8_kernel(const float* __restrict__ pos,
                                const int* __restrict__ species,
                                unsigned long long* __restrict__ tab8, int n) {
    int i = blockIdx.x * blockDim.x + threadIdx.x;
    if (i < n) {
        unsigned int ux = (unsigned int)(pos[3 * i]     * QSCALE + 0.5f) & 0xFFFFu;
        unsigned int uy = (unsigned int)(pos[3 * i + 1] * QSCALE + 0.5f) & 0xFFFFu;
        unsigned int uz = (unsigned int)(pos[3 * i + 2] * QSCALE + 0.5f) & 0xFFFFu;
        unsigned long long w = (unsigned long long)ux
                             | ((unsigned long long)uy << 16)
                             | ((unsigned long long)uz << 32)
                             | ((unsigned long long)(species[i] & 3) << 48);
        tab8[i] = w;
    }
}

// float4 pack (fallback path)
__global__ void lj_pack_kernel(const float* __restrict__ pos,
                               const int* __restrict__ species,
                               float4* __restrict__ packed, int n) {
    int i = blockIdx.x * blockDim.x + threadIdx.x;
    if (i < n) {
        float4 p;
        p.x = pos[3 * i];
        p.y = pos[3 * i + 1];
        p.z = pos[3 * i + 2];
        p.w = __int_as_float(species[i]);
        packed[i] = p;
    }
}

// Encode: round he's f32 bits to 12 mantissa bits, pack local id in low 11.
__device__ __forceinline__ unsigned int lj_encode(float he) {
    unsigned int u = __float_as_uint(he);
    return (u + 0x400u) & 0xFFFFF800u;
}

__global__ __launch_bounds__(256) void lj_passA_kernel(
    const unsigned long long* __restrict__ tab8,
    const float* __restrict__ cell,
    const float* __restrict__ sigma_tab,
    const float* __restrict__ eps_tab,
    const float* __restrict__ shift_tab,
    const int* __restrict__ pair_i,
    const int* __restrict__ pair_j,
    const int* __restrict__ shifts,
    unsigned int* __restrict__ record_buf,
    int* __restrict__ cursor,
    int cap, int nb, int P)
{
    __shared__ float s_sig6[16];
    __shared__ float s_eps4[16];
    __shared__ float s_shift[16];
    __shared__ float s_cell[9];
    __shared__ int hist[256];
    __shared__ int basev[256];
    int t = threadIdx.x;
    if (t < 16) {
        float s = sigma_tab[t];
        float s3 = s * s * s;
        s_sig6[t] = s3 * s3;
        s_eps4[t] = 4.0f * eps_tab[t];
        s_shift[t] = shift_tab[t];
    }
    if (t < 9) s_cell[t] = cell[t];
    hist[t] = 0;
    __syncthreads();

    float c00 = s_cell[0], c01 = s_cell[1], c02 = s_cell[2];
    float c10 = s_cell[3], c11 = s_cell[4], c12 = s_cell[5];
    float c20 = s_cell[6], c21 = s_cell[7], c22 = s_cell[8];

    long base = (long)(blockIdx.x * (long)blockDim.x + t) * 4;

    int   ai[4], aj[4];
    float hev[4];
    int   sloti[4], slotj[4];
    bool  valid[4];

    if (base + 3 < P) {
        int4 pi4 = *(const int4*)(pair_i + base);
        int4 pj4 = *(const int4*)(pair_j + base);
        int4 sA = *(const int4*)(shifts + base * 3);
        int4 sB = *(const int4*)(shifts + base * 3 + 4);
        int4 sC = *(const int4*)(shifts + base * 3 + 8);
        int pis[4] = {pi4.x, pi4.y, pi4.z, pi4.w};
        int pjs[4] = {pj4.x, pj4.y, pj4.z, pj4.w};
        int shv[12] = {sA.x, sA.y, sA.z, sA.w, sB.x, sB.y, sB.z, sB.w,
                       sC.x, sC.y, sC.z, sC.w};
#pragma unroll
        for (int k = 0; k < 4; ++k) {
            int i = pis[k], j = pjs[k];
            float fx = (float)shv[3 * k], fy = (float)shv[3 * k + 1], fz = (float)shv[3 * k + 2];
            unsigned long long gi = tab8[i];
            unsigned long long gj = tab8[j];
            int xi = (int)(gi & 0xFFFFu), yi = (int)((gi >> 16) & 0xFFFFu), zi = (int)((gi >> 32) & 0xFFFFu);
            int xj = (int)(gj & 0xFFFFu), yj = (int)((gj >> 16) & 0xFFFFu), zj = (int)((gj >> 32) & 0xFFFFu);
            float dlx = (float)(xj - xi) * QINV;
            float dly = (float)(yj - yi) * QINV;
            float dlz = (float)(zj - zi) * QINV;
            float dx = dlx + fx * c00 + fy * c10 + fz * c20;
            float dy = dly + fx * c01 + fy * c11 + fz * c21;
            float dz = dlz + fx * c02 + fy * c12 + fz * c22;
            float r2 = dx * dx + dy * dy + dz * dz;
            float r6 = r2 * r2 * r2;
            int idx = (int)(gi >> 48) * 4 + (int)(gj >> 48);
            float sr6 = s_sig6[idx] / r6;
            float sr12 = sr6 * sr6;
            hev[k] = 0.5f * (s_eps4[idx] * (sr12 - sr6) - s_shift[idx]);
            ai[k] = i; aj[k] = j; valid[k] = true;
        }
    } else {
#pragma unroll
        for (int k = 0; k < 4; ++k) {
            long p = base + k;
            valid[k] = (p < P);
            ai[k] = 0; aj[k] = 0; hev[k] = 0.0f;
            if (valid[k]) {
                int i = pair_i[p], j = pair_j[p];
                float fx = (float)shifts[3 * p], fy = (float)shifts[3 * p + 1], fz = (float)shifts[3 * p + 2];
                unsigned long long gi = tab8[i];
                unsigned long long gj = tab8[j];
                int xi = (int)(gi & 0xFFFFu), yi = (int)((gi >> 16) & 0xFFFFu), zi = (int)((gi >> 32) & 0xFFFFu);
                int xj = (int)(gj & 0xFFFFu), yj = (int)((gj >> 16) & 0xFFFFu), zj = (int)((gj >> 32) & 0xFFFFu);
                float dlx = (float)(xj - xi) * QINV;
                float dly = (float)(yj - yi) * QINV;
                float dlz = (float)(zj - zi) * QINV;
                float dx = dlx + fx * c00 + fy * c10 + fz * c20;
                float dy = dly + fx * c01 + fy * c11 + fz * c21;
                float dz = dlz + fx * c02 + fy * c12 + fz * c22;
                float r2 = dx * dx + dy * dy + dz * dz;
                float r6 = r2 * r2 * r2;
                int idx = (int)(gi >> 48) * 4 + (int)(gj >> 48);
                float sr6 = s_sig6[idx] / r6;
                float sr12 = sr6 * sr6;
                hev[k] = 0.5f * (s_eps4[idx] * (sr12 - sr6) - s_shift[idx]);
                ai[k] = i; aj[k] = j;
            }
        }
    }

    // Histogram phase (LDS atomics).
#pragma unroll
    for (int k = 0; k < 4; ++k) {
        if (valid[k]) {
            sloti[k] = atomicAdd(&hist[ai[k] >> BUCKET_SHIFT], 1);
            slotj[k] = atomicAdd(&hist[aj[k] >> BUCKET_SHIFT], 1);
        } else {
            sloti[k] = 0; slotj[k] = 0;
        }
    }
    __syncthreads();

    // Reserve per-bucket space: ONE global atomic per touched bucket per block.
    if (t < nb) {
        int h = hist[t];
        basev[t] = (h > 0) ? atomicAdd(&cursor[t], h) : 0;
    }
    __syncthreads();

    // Write records.
#pragma unroll
    for (int k = 0; k < 4; ++k) {
        if (valid[k]) {
            unsigned int u = lj_encode(hev[k]);
            int bi = ai[k] >> BUCKET_SHIFT;
            int wi = basev[bi] + sloti[k];
            if (wi < (bi + 1) * cap)
                record_buf[wi] = u | (unsigned int)(ai[k] & (BUCKET_SIZE - 1));
            int bj = aj[k] >> BUCKET_SHIFT;
            int wj = basev[bj] + slotj[k];
            if (wj < (bj + 1) * cap)
                record_buf[wj] = u | (unsigned int)(aj[k] & (BUCKET_SIZE - 1));
        }
    }
}

// One block per (bucket, slice). Accumulate slice's records into LDS, write
// an 8KB partial to ws.
__global__ __launch_bounds__(256) void lj_passB_kernel(
    const unsigned int* __restrict__ record_buf,
    const int* __restrict__ cursor,
    float* __restrict__ partial,
    int cap)
{
    __shared__ float e[BUCKET_SIZE];
    int blk = blockIdx.x;
    int b = blk >> 3;            // bucket
    int s = blk & (SLICES - 1);  // slice
    int t = threadIdx.x;
#pragma unroll
    for (int k = 0; k < 8; ++k) e[t + 256 * k] = 0.0f;
    __syncthreads();

    int begin = b * cap;
    int count = cursor[b] - begin;
    if (count > cap) count = cap;

    int ngroups = (count + 7) >> 3;
    int gps = (ngroups + SLICES - 1) / SLICES;
    int g0 = s * gps;
    int g1 = g0 + gps;
    if (g1 > ngroups) g1 = ngroups;

    for (int g = g0 + t; g < g1; g += 256) {
        int r0 = g * 8;
        const unsigned int* rp = record_buf + begin + r0;
        if (r0 + 8 <= count) {
            int4 a = *(const int4*)(rp);
            int4 c = *(const int4*)(rp + 4);
            unsigned int w0 = (unsigned int)a.x, w1 = (unsigned int)a.y;
            unsigned int w2 = (unsigned int)a.z, w3 = (unsigned int)a.w;
            unsigned int w4 = (unsigned int)c.x, w5 = (unsigned int)c.y;
            unsigned int w6 = (unsigned int)c.z, w7 = (unsigned int)c.w;
            atomicAdd(&e[w0 & 2047u], __uint_as_float(w0 & 0xFFFFF800u));
            atomicAdd(&e[w1 & 2047u], __uint_as_float(w1 & 0xFFFFF800u));
            atomicAdd(&e[w2 & 2047u], __uint_as_float(w2 & 0xFFFFF800u));
            atomicAdd(&e[w3 & 2047u], __uint_as_float(w3 & 0xFFFFF800u));
            atomicAdd(&e[w4 & 2047u], __uint_as_float(w4 & 0xFFFFF800u));
            atomicAdd(&e[w5 & 2047u], __uint_as_float(w5 & 0xFFFFF800u));
            atomicAdd(&e[w6 & 2047u], __uint_as_float(w6 & 0xFFFFF800u));
            atomicAdd(&e[w7 & 2047u], __uint_as_float(w7 & 0xFFFFF800u));
        } else {
            for (int r = r0; r < count; ++r) {
                unsigned int w = record_buf[begin + r];
                atomicAdd(&e[w & 2047u], __uint_as_float(w & 0xFFFFF800u));
            }
        }
    }
    __syncthreads();

    float* pb = partial + (long)blk * BUCKET_SIZE;
#pragma unroll
    for (int k = 0; k < 8; ++k) pb[t + 256 * k] = e[t + 256 * k];
}

// energy[i] = sum of SLICES partials for i's bucket.
__global__ void lj_reduce_kernel(const float* __restrict__ partial,
                                 float* __restrict__ energy, int N) {
    int i = blockIdx.x * blockDim.x + threadIdx.x;
    if (i < N) {
        int b = i >> BUCKET_SHIFT;
        int l = i & (BUCKET_SIZE - 1);
        const float* pb = partial + ((long)b * SLICES) * BUCKET_SIZE + l;
        float s = 0.0f;
#pragma unroll
        for (int k = 0; k < SLICES; ++k) s += pb[(long)k * BUCKET_SIZE];
        energy[i] = s;
    }
}

// ------------------- R7 packed fallback (proven, 1561 us) -------------------
__device__ __forceinline__ void lj_one_pair_packed(
    int i, int j, float fx, float fy, float fz,
    const float4* __restrict__ packed,
    const float* s_sig6, const float* s_eps4, const float* s_shift,
    float c00, float c01, float c02,
    float c10, float c11, float c12,
    float c20, float c21, float c22,
    float* __restrict__ energy)
{
    float4 gi = packed[i];
    float4 gj = packed[j];
    float dx = gj.x - gi.x + fx * c00 + fy * c10 + fz * c20;
    float dy = gj.y - gi.y + fx * c01 + fy * c11 + fz * c21;
    float dz = gj.z - gi.z + fx * c02 + fy * c12 + fz * c22;
    float r2 = dx * dx + dy * dy + dz * dz;
    float r6 = r2 * r2 * r2;
    int idx = __float_as_int(gi.w) * 4 + __float_as_int(gj.w);
    float sr6 = s_sig6[idx] / r6;
    float sr12 = sr6 * sr6;
    float he = 0.5f * (s_eps4[idx] * (sr12 - sr6) - s_shift[idx]);
    atomicAdd(energy + i, he);
    atomicAdd(energy + j, he);
}

__global__ __launch_bounds__(256) void lj_pairs_packed_kernel(
    const float4* __restrict__ packed,
    const float* __restrict__ cell,
    const float* __restrict__ sigma_tab,
    const float* __restrict__ eps_tab,
    const float* __restrict__ shift_tab,
    const int* __restrict__ pair_i,
    const int* __restrict__ pair_j,
    const int* __restrict__ shifts,
    float* __restrict__ energy,
    int P)
{
    __shared__ float s_sig6[16];
    __shared__ float s_eps4[16];
    __shared__ float s_shift[16];
    __shared__ float s_cell[9];
    int t = threadIdx.x;
    if (t < 16) {
        float s = sigma_tab[t];
        float s3 = s * s * s;
        s_sig6[t] = s3 * s3;
        s_eps4[t] = 4.0f * eps_tab[t];
        s_shift[t] = shift_tab[t];
    }
    if (t < 9) s_cell[t] = cell[t];
    __syncthreads();

    float c00 = s_cell[0], c01 = s_cell[1], c02 = s_cell[2];
    float c10 = s_cell[3], c11 = s_cell[4], c12 = s_cell[5];
    float c20 = s_cell[6], c21 = s_cell[7], c22 = s_cell[8];

    long base = (long)(blockIdx.x * (long)blockDim.x + t) * 4;
    if (base + 3 < P) {
        int4 pi4 = *(const int4*)(pair_i + base);
        int4 pj4 = *(const int4*)(pair_j + base);
        int4 sA = *(const int4*)(shifts + base * 3);
        int4 sB = *(const int4*)(shifts + base * 3 + 4);
        int4 sC = *(const int4*)(shifts + base * 3 + 8);
        int pis[4] = {pi4.x, pi4.y, pi4.z, pi4.w};
        int pjs[4] = {pj4.x, pj4.y, pj4.z, pj4.w};
        int shv[12] = {sA.x, sA.y, sA.z, sA.w, sB.x, sB.y, sB.z, sB.w,
                       sC.x, sC.y, sC.z, sC.w};
#pragma unroll
        for (int k = 0; k < 4; ++k) {
            lj_one_pair_packed(pis[k], pjs[k],
                        (float)shv[3 * k], (float)shv[3 * k + 1], (float)shv[3 * k + 2],
                        packed, s_sig6, s_eps4, s_shift,
                        c00, c01, c02, c10, c11, c12, c20, c21, c22, energy);
        }
    } else {
        for (long p = base; p < P; ++p) {
            lj_one_pair_packed(pair_i[p], pair_j[p],
                        (float)shifts[3 * p], (float)shifts[3 * p + 1], (float)shifts[3 * p + 2],
                        packed, s_sig6, s_eps4, s_shift,
                        c00, c01, c02, c10, c11, c12, c20, c21, c22, energy);
        }
    }
}

// --------------------- R1 fallback (no workspace at all) --------------------
__device__ __forceinline__ void lj_one_pair(
    int i, int j, float fx, float fy, float fz,
    const float* __restrict__ pos,
    const int* __restrict__ species,
    const float* s_sig6, const float* s_eps4, const float* s_shift,
    float c00, float c01, float c02,
    float c10, float c11, float c12,
    float c20, float c21, float c22,
    float* __restrict__ energy)
{
    float dx = pos[3 * j]     - pos[3 * i]     + fx * c00 + fy * c10 + fz * c20;
    float dy = pos[3 * j + 1] - pos[3 * i + 1] + fx * c01 + fy * c11 + fz * c21;
    float dz = pos[3 * j + 2] - pos[3 * i + 2] + fx * c02 + fy * c12 + fz * c22;
    float r2 = dx * dx + dy * dy + dz * dz;
    float r6 = r2 * r2 * r2;
    int idx = species[i] * 4 + species[j];
    float sr6 = s_sig6[idx] / r6;
    float sr12 = sr6 * sr6;
    float he = 0.5f * (s_eps4[idx] * (sr12 - sr6) - s_shift[idx]);
    atomicAdd(energy + i, he);
    atomicAdd(energy + j, he);
}

__global__ __launch_bounds__(256) void lj_pairs_kernel(
    const float* __restrict__ pos,
    const float* __restrict__ cell,
    const float* __restrict__ sigma_tab,
    const float* __restrict__ eps_tab,
    const float* __restrict__ shift_tab,
    const int* __restrict__ species,
    const int* __restrict__ pair_i,
    const int* __restrict__ pair_j,
    const int* __restrict__ shifts,
    float* __restrict__ energy,
    int P)
{
    __shared__ float s_sig6[16];
    __shared__ float s_eps4[16];
    __shared__ float s_shift[16];
    __shared__ float s_cell[9];
    int t = threadIdx.x;
    if (t < 16) {
        float s = sigma_tab[t];
        float s3 = s * s * s;
        s_sig6[t] = s3 * s3;
        s_eps4[t] = 4.0f * eps_tab[t];
        s_shift[t] = shift_tab[t];
    }
    if (t < 9) s_cell[t] = cell[t];
    __syncthreads();

    float c00 = s_cell[0], c01 = s_cell[1], c02 = s_cell[2];
    float c10 = s_cell[3], c11 = s_cell[4], c12 = s_cell[5];
    float c20 = s_cell[6], c21 = s_cell[7], c22 = s_cell[8];

    long base = (long)(blockIdx.x * (long)blockDim.x + t) * 4;
    if (base + 3 < P) {
        int4 pi4 = *(const int4*)(pair_i + base);
        int4 pj4 = *(const int4*)(pair_j + base);
        int4 sA = *(const int4*)(shifts + base * 3);
        int4 sB = *(const int4*)(shifts + base * 3 + 4);
        int4 sC = *(const int4*)(shifts + base * 3 + 8);
        int pis[4] = {pi4.x, pi4.y, pi4.z, pi4.w};
        int pjs[4] = {pj4.x, pj4.y, pj4.z, pj4.w};
        int shv[12] = {sA.x, sA.y, sA.z, sA.w, sB.x, sB.y, sB.z, sB.w,
                       sC.x, sC.y, sC.z, sC.w};
#pragma unroll
        for (int k = 0; k < 4; ++k) {
            lj_one_pair(pis[k], pjs[k],
                        (float)shv[3 * k], (float)shv[3 * k + 1], (float)shv[3 * k + 2],
                        pos, species, s_sig6, s_eps4, s_shift,
                        c00, c01, c02, c10, c11, c12, c20, c21, c22, energy);
        }
    } else {
        for (long p = base; p < P; ++p) {
            lj_one_pair(pair_i[p], pair_j[p],
                        (float)shifts[3 * p], (float)shifts[3 * p + 1], (float)shifts[3 * p + 2],
                        pos, species, s_sig6, s_eps4, s_shift,
                        c00, c01, c02, c10, c11, c12, c20, c21, c22, energy);
        }
    }
}

extern "C" void kernel_launch(void* const* d_in, const int* in_sizes, int n_in,
                              void* d_out, int out_size, void* d_ws, size_t ws_size,
                              hipStream_t stream) {
    const float* positions = (const float*)d_in[0];
    const float* cell      = (const float*)d_in[1];
    const float* sigma_tab = (const float*)d_in[2];
    const float* eps_tab   = (const float*)d_in[3];
    const float* shift_tab = (const float*)d_in[4];
    const int*   species   = (const int*)d_in[5];
    const int*   pair_i    = (const int*)d_in[6];
    const int*   pair_j    = (const int*)d_in[7];
    const int*   shifts    = (const int*)d_in[8];
    float* energy = (float*)d_out;

    const int N = out_size;
    const int P = in_sizes[6];

    const int threads = 256;
    const int ablocks = (N + threads - 1) / threads;
    const int pblocks4 = (int)((((long)P + 3) / 4 + threads - 1) / threads);

    // Bucket path sizing.
    const int nb = (N + BUCKET_SIZE - 1) / BUCKET_SIZE;
    long avg = (2L * P) / (nb > 0 ? nb : 1);
    long capl = (avg + avg / 50 + 512 + 1023) & ~1023L;
    const int cap = (int)capl;
    // ws layout: [records nb*cap u32][tab8 N u64][cursor nb i32][partial nb*SLICES*2048 f32]
    const size_t rec_bytes  = (size_t)nb * (size_t)cap * 4u;
    const size_t tab_bytes  = (size_t)N * 8u;
    const size_t cur_bytes  = (size_t)nb * 4u;
    const size_t part_bytes = (size_t)nb * SLICES * BUCKET_SIZE * 4u;
    const size_t need_bucket = rec_bytes + tab_bytes + cur_bytes + part_bytes;
    const size_t need_pack   = (size_t)N * 16u;

    const bool has_ws = (d_ws != nullptr);
    const bool sane = (nb > 0) && (nb <= 256) && ((long)nb * cap < 2000000000L);
    const bool use_bucket = has_ws && sane && (ws_size >= need_bucket);
    const bool use_pack   = has_ws && !use_bucket && (ws_size >= need_pack);

    if (use_bucket) {
        unsigned int* record_buf = (unsigned int*)d_ws;
        unsigned long long* tab8 = (unsigned long long*)((char*)d_ws + rec_bytes);
        int* cursor = (int*)((char*)d_ws + rec_bytes + tab_bytes);
        float* partial = (float*)((char*)d_ws + rec_bytes + tab_bytes + cur_bytes);

        lj_cursor_init_kernel<<<1, 256, 0, stream>>>(cursor, nb, cap);
        lj_pack8_kernel<<<ablocks, threads, 0, stream>>>(positions, species, tab8, N);
        lj_passA_kernel<<<pblocks4, threads, 0, stream>>>(
            tab8, cell, sigma_tab, eps_tab, shift_tab,
            pair_i, pair_j, shifts, record_buf, cursor, cap, nb, P);
        lj_passB_kernel<<<nb * SLICES, threads, 0, stream>>>(record_buf, cursor, partial, cap);
        lj_reduce_kernel<<<ablocks, threads, 0, stream>>>(partial, energy, N);
    } else if (use_pack) {
        float4* packed = (float4*)d_ws;
        lj_zero_kernel<<<ablocks, threads, 0, stream>>>(energy, N);
        lj_pack_kernel<<<ablocks, threads, 0, stream>>>(positions, species, packed, N);
        lj_pairs_packed_kernel<<<pblocks4, threads, 0, stream>>>(
            packed, cell, sigma_tab, eps_tab, shift_tab,
            pair_i, pair_j, shifts, energy, P);
    } else {
        lj_zero_kernel<<<ablocks, threads, 0, stream>>>(energy, N);
        lj_pairs_kernel<<<pblocks4, threads, 0, stream>>>(
            positions, cell, sigma_tab, eps_tab, shift_tab, species,
            pair_i, pair_j, shifts, energy, P);
    }
}

// Round 12
// 822.340 us; speedup vs baseline: 1.0969x; 1.0016x over previous
//
#include <hip/hip_runtime.h>

// ---------------------------------------------------------------------------
// LennardJones per-atom energy — bucketed two-pass.
//
// R12: passA block 256 -> 1024 threads (same 4 pairs/thread structure).
// 8192 records/block over 245 buckets = ~33 records (134B) per bucket-run
// instead of 8.4 (33B) -> scattered record-write lines drop ~3.5x (3.8M ->
// ~1.1M + RMW fills likewise); cursor atomics 4x fewer. Cursor init folded
// into pack kernel. Everything else identical to R11.
// ws-guarded; fallbacks: R7 packed float4, then R1.
// ---------------------------------------------------------------------------

#define BUCKET_SHIFT 11
#define BUCKET_SIZE  2048
#define SLICES       8
#define QSCALE       2048.0f
#define QINV         (1.0f / 2048.0f)

__global__ void lj_zero_kernel(float* __restrict__ out, long n) {
    long i = (long)blockIdx.x * blockDim.x + threadIdx.x;
    if (i < n) out[i] = 0.0f;
}

// tab8[a] = x_u16 | y_u16<<16 | z_u16<<32 | species<<48  (coords * 2048)
// Also initializes cursor[b] = b * cap (folded to save a dispatch).
__global__ void lj_pack8_kernel(const float* __restrict__ pos,
                                const int* __restrict__ species,
                                unsigned long long* __restrict__ tab8,
                                int* __restrict__ cursor,
                                int nb, int cap, int n) {
    int i = blockIdx.x * blockDim.x + threadIdx.x;
    if (i < n) {
        unsigned int ux = (unsigned int)(pos[3 * i]     * QSCALE + 0.5f) & 0xFFFFu;
        unsigned int uy = (unsigned int)(pos[3 * i + 1] * QSCALE + 0.5f) & 0xFFFFu;
        unsigned int uz = (unsigned int)(pos[3 * i + 2] * QSCALE + 0.5f) & 0xFFFFu;
        unsigned long long w = (unsigned long long)ux
                             | ((unsigned long long)uy << 16)
                             | ((unsigned long long)uz << 32)
                             | ((unsigned long long)(species[i] & 3) << 48);
        tab8[i] = w;
    }
    if (i < nb) cursor[i] = i * cap;
}

// float4 pack (fallback path)
__global__ void lj_pack_kernel(const float* __restrict__ pos,
                               const int* __restrict__ species,
                               float4* __restrict__ packed, int n) {
    int i = blockIdx.x * blockDim.x + threadIdx.x;
    if (i < n) {
        float4 p;
        p.x = pos[3 * i];
        p.y = pos[3 * i + 1];
        p.z = pos[3 * i + 2];
        p.w = __int_as_float(species[i]);
        packed[i] = p;
    }
}

// Encode: round he's f32 bits to 12 mantissa bits, pack local id in low 11.
__device__ __forceinline__ unsigned int lj_encode(float he) {
    unsigned int u = __float_as_uint(he);
    return (u + 0x400u) & 0xFFFFF800u;
}

__global__ __launch_bounds__(1024) void lj_passA_kernel(
    const unsigned long long* __restrict__ tab8,
    const float* __restrict__ cell,
    const float* __restrict__ sigma_tab,
    const float* __restrict__ eps_tab,
    const float* __restrict__ shift_tab,
    const int* __restrict__ pair_i,
    const int* __restrict__ pair_j,
    const int* __restrict__ shifts,
    unsigned int* __restrict__ record_buf,
    int* __restrict__ cursor,
    int cap, int nb, int P)
{
    __shared__ float s_sig6[16];
    __shared__ float s_eps4[16];
    __shared__ float s_shift[16];
    __shared__ float s_cell[9];
    __shared__ int hist[256];
    __shared__ int basev[256];
    int t = threadIdx.x;
    if (t < 16) {
        float s = sigma_tab[t];
        float s3 = s * s * s;
        s_sig6[t] = s3 * s3;
        s_eps4[t] = 4.0f * eps_tab[t];
        s_shift[t] = shift_tab[t];
    }
    if (t < 9) s_cell[t] = cell[t];
    if (t < 256) hist[t] = 0;
    __syncthreads();

    float c00 = s_cell[0], c01 = s_cell[1], c02 = s_cell[2];
    float c10 = s_cell[3], c11 = s_cell[4], c12 = s_cell[5];
    float c20 = s_cell[6], c21 = s_cell[7], c22 = s_cell[8];

    long base = (long)(blockIdx.x * (long)blockDim.x + t) * 4;

    int   ai[4], aj[4];
    float hev[4];
    int   sloti[4], slotj[4];
    bool  valid[4];

    if (base + 3 < P) {
        int4 pi4 = *(const int4*)(pair_i + base);
        int4 pj4 = *(const int4*)(pair_j + base);
        int4 sA = *(const int4*)(shifts + base * 3);
        int4 sB = *(const int4*)(shifts + base * 3 + 4);
        int4 sC = *(const int4*)(shifts + base * 3 + 8);
        int pis[4] = {pi4.x, pi4.y, pi4.z, pi4.w};
        int pjs[4] = {pj4.x, pj4.y, pj4.z, pj4.w};
        int shv[12] = {sA.x, sA.y, sA.z, sA.w, sB.x, sB.y, sB.z, sB.w,
                       sC.x, sC.y, sC.z, sC.w};
#pragma unroll
        for (int k = 0; k < 4; ++k) {
            int i = pis[k], j = pjs[k];
            float fx = (float)shv[3 * k], fy = (float)shv[3 * k + 1], fz = (float)shv[3 * k + 2];
            unsigned long long gi = tab8[i];
            unsigned long long gj = tab8[j];
            int xi = (int)(gi & 0xFFFFu), yi = (int)((gi >> 16) & 0xFFFFu), zi = (int)((gi >> 32) & 0xFFFFu);
            int xj = (int)(gj & 0xFFFFu), yj = (int)((gj >> 16) & 0xFFFFu), zj = (int)((gj >> 32) & 0xFFFFu);
            float dlx = (float)(xj - xi) * QINV;
            float dly = (float)(yj - yi) * QINV;
            float dlz = (float)(zj - zi) * QINV;
            float dx = dlx + fx * c00 + fy * c10 + fz * c20;
            float dy = dly + fx * c01 + fy * c11 + fz * c21;
            float dz = dlz + fx * c02 + fy * c12 + fz * c22;
            float r2 = dx * dx + dy * dy + dz * dz;
            float r6 = r2 * r2 * r2;
            int idx = (int)(gi >> 48) * 4 + (int)(gj >> 48);
            float sr6 = s_sig6[idx] / r6;
            float sr12 = sr6 * sr6;
            hev[k] = 0.5f * (s_eps4[idx] * (sr12 - sr6) - s_shift[idx]);
            ai[k] = i; aj[k] = j; valid[k] = true;
        }
    } else {
#pragma unroll
        for (int k = 0; k < 4; ++k) {
            long p = base + k;
            valid[k] = (p < P);
            ai[k] = 0; aj[k] = 0; hev[k] = 0.0f;
            if (valid[k]) {
                int i = pair_i[p], j = pair_j[p];
                float fx = (float)shifts[3 * p], fy = (float)shifts[3 * p + 1], fz = (float)shifts[3 * p + 2];
                unsigned long long gi = tab8[i];
                unsigned long long gj = tab8[j];
                int xi = (int)(gi & 0xFFFFu), yi = (int)((gi >> 16) & 0xFFFFu), zi = (int)((gi >> 32) & 0xFFFFu);
                int xj = (int)(gj & 0xFFFFu), yj = (int)((gj >> 16) & 0xFFFFu), zj = (int)((gj >> 32) & 0xFFFFu);
                float dlx = (float)(xj - xi) * QINV;
                float dly = (float)(yj - yi) * QINV;
                float dlz = (float)(zj - zi) * QINV;
                float dx = dlx + fx * c00 + fy * c10 + fz * c20;
                float dy = dly + fx * c01 + fy * c11 + fz * c21;
                float dz = dlz + fx * c02 + fy * c12 + fz * c22;
                float r2 = dx * dx + dy * dy + dz * dz;
                float r6 = r2 * r2 * r2;
                int idx = (int)(gi >> 48) * 4 + (int)(gj >> 48);
                float sr6 = s_sig6[idx] / r6;
                float sr12 = sr6 * sr6;
                hev[k] = 0.5f * (s_eps4[idx] * (sr12 - sr6) - s_shift[idx]);
                ai[k] = i; aj[k] = j;
            }
        }
    }

    // Histogram phase (LDS atomics).
#pragma unroll
    for (int k = 0; k < 4; ++k) {
        if (valid[k]) {
            sloti[k] = atomicAdd(&hist[ai[k] >> BUCKET_SHIFT], 1);
            slotj[k] = atomicAdd(&hist[aj[k] >> BUCKET_SHIFT], 1);
        } else {
            sloti[k] = 0; slotj[k] = 0;
        }
    }
    __syncthreads();

    // Reserve per-bucket space: ONE global atomic per touched bucket per block.
    if (t < nb) {
        int h = hist[t];
        basev[t] = (h > 0) ? atomicAdd(&cursor[t], h) : 0;
    }
    __syncthreads();

    // Write records.
#pragma unroll
    for (int k = 0; k < 4; ++k) {
        if (valid[k]) {
            unsigned int u = lj_encode(hev[k]);
            int bi = ai[k] >> BUCKET_SHIFT;
            int wi = basev[bi] + sloti[k];
            if (wi < (bi + 1) * cap)
                record_buf[wi] = u | (unsigned int)(ai[k] & (BUCKET_SIZE - 1));
            int bj = aj[k] >> BUCKET_SHIFT;
            int wj = basev[bj] + slotj[k];
            if (wj < (bj + 1) * cap)
                record_buf[wj] = u | (unsigned int)(aj[k] & (BUCKET_SIZE - 1));
        }
    }
}

// One block per (bucket, slice). Accumulate slice's records into LDS, write
// an 8KB partial to ws.
__global__ __launch_bounds__(256) void lj_passB_kernel(
    const unsigned int* __restrict__ record_buf,
    const int* __restrict__ cursor,
    float* __restrict__ partial,
    int cap)
{
    __shared__ float e[BUCKET_SIZE];
    int blk = blockIdx.x;
    int b = blk >> 3;            // bucket
    int s = blk & (SLICES - 1);  // slice
    int t = threadIdx.x;
#pragma unroll
    for (int k = 0; k < 8; ++k) e[t + 256 * k] = 0.0f;
    __syncthreads();

    int begin = b * cap;
    int count = cursor[b] - begin;
    if (count > cap) count = cap;

    int ngroups = (count + 7) >> 3;
    int gps = (ngroups + SLICES - 1) / SLICES;
    int g0 = s * gps;
    int g1 = g0 + gps;
    if (g1 > ngroups) g1 = ngroups;

    for (int g = g0 + t; g < g1; g += 256) {
        int r0 = g * 8;
        const unsigned int* rp = record_buf + begin + r0;
        if (r0 + 8 <= count) {
            int4 a = *(const int4*)(rp);
            int4 c = *(const int4*)(rp + 4);
            unsigned int w0 = (unsigned int)a.x, w1 = (unsigned int)a.y;
            unsigned int w2 = (unsigned int)a.z, w3 = (unsigned int)a.w;
            unsigned int w4 = (unsigned int)c.x, w5 = (unsigned int)c.y;
            unsigned int w6 = (unsigned int)c.z, w7 = (unsigned int)c.w;
            atomicAdd(&e[w0 & 2047u], __uint_as_float(w0 & 0xFFFFF800u));
            atomicAdd(&e[w1 & 2047u], __uint_as_float(w1 & 0xFFFFF800u));
            atomicAdd(&e[w2 & 2047u], __uint_as_float(w2 & 0xFFFFF800u));
            atomicAdd(&e[w3 & 2047u], __uint_as_float(w3 & 0xFFFFF800u));
            atomicAdd(&e[w4 & 2047u], __uint_as_float(w4 & 0xFFFFF800u));
            atomicAdd(&e[w5 & 2047u], __uint_as_float(w5 & 0xFFFFF800u));
            atomicAdd(&e[w6 & 2047u], __uint_as_float(w6 & 0xFFFFF800u));
            atomicAdd(&e[w7 & 2047u], __uint_as_float(w7 & 0xFFFFF800u));
        } else {
            for (int r = r0; r < count; ++r) {
                unsigned int w = record_buf[begin + r];
                atomicAdd(&e[w & 2047u], __uint_as_float(w & 0xFFFFF800u));
            }
        }
    }
    __syncthreads();

    float* pb = partial + (long)blk * BUCKET_SIZE;
#pragma unroll
    for (int k = 0; k < 8; ++k) pb[t + 256 * k] = e[t + 256 * k];
}

// energy[i] = sum of SLICES partials for i's bucket.
__global__ void lj_reduce_kernel(const float* __restrict__ partial,
                                 float* __restrict__ energy, int N) {
    int i = blockIdx.x * blockDim.x + threadIdx.x;
    if (i < N) {
        int b = i >> BUCKET_SHIFT;
        int l = i & (BUCKET_SIZE - 1);
        const float* pb = partial + ((long)b * SLICES) * BUCKET_SIZE + l;
        float s = 0.0f;
#pragma unroll
        for (int k = 0; k < SLICES; ++k) s += pb[(long)k * BUCKET_SIZE];
        energy[i] = s;
    }
}

// ------------------- R7 packed fallback (proven, 1561 us) -------------------
__device__ __forceinline__ void lj_one_pair_packed(
    int i, int j, float fx, float fy, float fz,
    const float4* __restrict__ packed,
    const float* s_sig6, const float* s_eps4, const float* s_shift,
    float c00, float c01, float c02,
    float c10, float c11, float c12,
    float c20, float c21, float c22,
    float* __restrict__ energy)
{
    float4 gi = packed[i];
    float4 gj = packed[j];
    float dx = gj.x - gi.x + fx * c00 + fy * c10 + fz * c20;
    float dy = gj.y - gi.y + fx * c01 + fy * c11 + fz * c21;
    float dz = gj.z - gi.z + fx * c02 + fy * c12 + fz * c22;
    float r2 = dx * dx + dy * dy + dz * dz;
    float r6 = r2 * r2 * r2;
    int idx = __float_as_int(gi.w) * 4 + __float_as_int(gj.w);
    float sr6 = s_sig6[idx] / r6;
    float sr12 = sr6 * sr6;
    float he = 0.5f * (s_eps4[idx] * (sr12 - sr6) - s_shift[idx]);
    atomicAdd(energy + i, he);
    atomicAdd(energy + j, he);
}

__global__ __launch_bounds__(256) void lj_pairs_packed_kernel(
    const float4* __restrict__ packed,
    const float* __restrict__ cell,
    const float* __restrict__ sigma_tab,
    const float* __restrict__ eps_tab,
    const float* __restrict__ shift_tab,
    const int* __restrict__ pair_i,
    const int* __restrict__ pair_j,
    const int* __restrict__ shifts,
    float* __restrict__ energy,
    int P)
{
    __shared__ float s_sig6[16];
    __shared__ float s_eps4[16];
    __shared__ float s_shift[16];
    __shared__ float s_cell[9];
    int t = threadIdx.x;
    if (t < 16) {
        float s = sigma_tab[t];
        float s3 = s * s * s;
        s_sig6[t] = s3 * s3;
        s_eps4[t] = 4.0f * eps_tab[t];
        s_shift[t] = shift_tab[t];
    }
    if (t < 9) s_cell[t] = cell[t];
    __syncthreads();

    float c00 = s_cell[0], c01 = s_cell[1], c02 = s_cell[2];
    float c10 = s_cell[3], c11 = s_cell[4], c12 = s_cell[5];
    float c20 = s_cell[6], c21 = s_cell[7], c22 = s_cell[8];

    long base = (long)(blockIdx.x * (long)blockDim.x + t) * 4;
    if (base + 3 < P) {
        int4 pi4 = *(const int4*)(pair_i + base);
        int4 pj4 = *(const int4*)(pair_j + base);
        int4 sA = *(const int4*)(shifts + base * 3);
        int4 sB = *(const int4*)(shifts + base * 3 + 4);
        int4 sC = *(const int4*)(shifts + base * 3 + 8);
        int pis[4] = {pi4.x, pi4.y, pi4.z, pi4.w};
        int pjs[4] = {pj4.x, pj4.y, pj4.z, pj4.w};
        int shv[12] = {sA.x, sA.y, sA.z, sA.w, sB.x, sB.y, sB.z, sB.w,
                       sC.x, sC.y, sC.z, sC.w};
#pragma unroll
        for (int k = 0; k < 4; ++k) {
            lj_one_pair_packed(pis[k], pjs[k],
                        (float)shv[3 * k], (float)shv[3 * k + 1], (float)shv[3 * k + 2],
                        packed, s_sig6, s_eps4, s_shift,
                        c00, c01, c02, c10, c11, c12, c20, c21, c22, energy);
        }
    } else {
        for (long p = base; p < P; ++p) {
            lj_one_pair_packed(pair_i[p], pair_j[p],
                        (float)shifts[3 * p], (float)shifts[3 * p + 1], (float)shifts[3 * p + 2],
                        packed, s_sig6, s_eps4, s_shift,
                        c00, c01, c02, c10, c11, c12, c20, c21, c22, energy);
        }
    }
}

// --------------------- R1 fallback (no workspace at all) --------------------
__device__ __forceinline__ void lj_one_pair(
    int i, int j, float fx, float fy, float fz,
    const float* __restrict__ pos,
    const int* __restrict__ species,
    const float* s_sig6, const float* s_eps4, const float* s_shift,
    float c00, float c01, float c02,
    float c10, float c11, float c12,
    float c20, float c21, float c22,
    float* __restrict__ energy)
{
    float dx = pos[3 * j]     - pos[3 * i]     + fx * c00 + fy * c10 + fz * c20;
    float dy = pos[3 * j + 1] - pos[3 * i + 1] + fx * c01 + fy * c11 + fz * c21;
    float dz = pos[3 * j + 2] - pos[3 * i + 2] + fx * c02 + fy * c12 + fz * c22;
    float r2 = dx * dx + dy * dy + dz * dz;
    float r6 = r2 * r2 * r2;
    int idx = species[i] * 4 + species[j];
    float sr6 = s_sig6[idx] / r6;
    float sr12 = sr6 * sr6;
    float he = 0.5f * (s_eps4[idx] * (sr12 - sr6) - s_shift[idx]);
    atomicAdd(energy + i, he);
    atomicAdd(energy + j, he);
}

__global__ __launch_bounds__(256) void lj_pairs_kernel(
    const float* __restrict__ pos,
    const float* __restrict__ cell,
    const float* __restrict__ sigma_tab,
    const float* __restrict__ eps_tab,
    const float* __restrict__ shift_tab,
    const int* __restrict__ species,
    const int* __restrict__ pair_i,
    const int* __restrict__ pair_j,
    const int* __restrict__ shifts,
    float* __restrict__ energy,
    int P)
{
    __shared__ float s_sig6[16];
    __shared__ float s_eps4[16];
    __shared__ float s_shift[16];
    __shared__ float s_cell[9];
    int t = threadIdx.x;
    if (t < 16) {
        float s = sigma_tab[t];
        float s3 = s * s * s;
        s_sig6[t] = s3 * s3;
        s_eps4[t] = 4.0f * eps_tab[t];
        s_shift[t] = shift_tab[t];
    }
    if (t < 9) s_cell[t] = cell[t];
    __syncthreads();

    float c00 = s_cell[0], c01 = s_cell[1], c02 = s_cell[2];
    float c10 = s_cell[3], c11 = s_cell[4], c12 = s_cell[5];
    float c20 = s_cell[6], c21 = s_cell[7], c22 = s_cell[8];

    long base = (long)(blockIdx.x * (long)blockDim.x + t) * 4;
    if (base + 3 < P) {
        int4 pi4 = *(const int4*)(pair_i + base);
        int4 pj4 = *(const int4*)(pair_j + base);
        int4 sA = *(const int4*)(shifts + base * 3);
        int4 sB = *(const int4*)(shifts + base * 3 + 4);
        int4 sC = *(const int4*)(shifts + base * 3 + 8);
        int pis[4] = {pi4.x, pi4.y, pi4.z, pi4.w};
        int pjs[4] = {pj4.x, pj4.y, pj4.z, pj4.w};
        int shv[12] = {sA.x, sA.y, sA.z, sA.w, sB.x, sB.y, sB.z, sB.w,
                       sC.x, sC.y, sC.z, sC.w};
#pragma unroll
        for (int k = 0; k < 4; ++k) {
            lj_one_pair(pis[k], pjs[k],
                        (float)shv[3 * k], (float)shv[3 * k + 1], (float)shv[3 * k + 2],
                        pos, species, s_sig6, s_eps4, s_shift,
                        c00, c01, c02, c10, c11, c12, c20, c21, c22, energy);
        }
    } else {
        for (long p = base; p < P; ++p) {
            lj_one_pair(pair_i[p], pair_j[p],
                        (float)shifts[3 * p], (float)shifts[3 * p + 1], (float)shifts[3 * p + 2],
                        pos, species, s_sig6, s_eps4, s_shift,
                        c00, c01, c02, c10, c11, c12, c20, c21, c22, energy);
        }
    }
}

extern "C" void kernel_launch(void* const* d_in, const int* in_sizes, int n_in,
                              void* d_out, int out_size, void* d_ws, size_t ws_size,
                              hipStream_t stream) {
    const float* positions = (const float*)d_in[0];
    const float* cell      = (const float*)d_in[1];
    const float* sigma_tab = (const float*)d_in[2];
    const float* eps_tab   = (const float*)d_in[3];
    const float* shift_tab = (const float*)d_in[4];
    const int*   species   = (const int*)d_in[5];
    const int*   pair_i    = (const int*)d_in[6];
    const int*   pair_j    = (const int*)d_in[7];
    const int*   shifts    = (const int*)d_in[8];
    float* energy = (float*)d_out;

    const int N = out_size;
    const int P = in_sizes[6];

    const int threads = 256;
    const int ablocks = (N + threads - 1) / threads;
    const int pblocks4 = (int)((((long)P + 3) / 4 + threads - 1) / threads);

    // Bucket path sizing.
    const int nb = (N + BUCKET_SIZE - 1) / BUCKET_SIZE;
    long avg = (2L * P) / (nb > 0 ? nb : 1);
    long capl = (avg + avg / 50 + 512 + 1023) & ~1023L;
    const int cap = (int)capl;
    // ws layout: [records nb*cap u32][tab8 N u64][cursor nb i32][partial nb*SLICES*2048 f32]
    const size_t rec_bytes  = (size_t)nb * (size_t)cap * 4u;
    const size_t tab_bytes  = (size_t)N * 8u;
    const size_t cur_bytes  = (size_t)nb * 4u;
    const size_t part_bytes = (size_t)nb * SLICES * BUCKET_SIZE * 4u;
    const size_t need_bucket = rec_bytes + tab_bytes + cur_bytes + part_bytes;
    const size_t need_pack   = (size_t)N * 16u;

    const bool has_ws = (d_ws != nullptr);
    const bool sane = (nb > 0) && (nb <= 256) && ((long)nb * cap < 2000000000L);
    const bool use_bucket = has_ws && sane && (ws_size >= need_bucket);
    const bool use_pack   = has_ws && !use_bucket && (ws_size >= need_pack);

    if (use_bucket) {
        unsigned int* record_buf = (unsigned int*)d_ws;
        unsigned long long* tab8 = (unsigned long long*)((char*)d_ws + rec_bytes);
        int* cursor = (int*)((char*)d_ws + rec_bytes + tab_bytes);
        float* partial = (float*)((char*)d_ws + rec_bytes + tab_bytes + cur_bytes);

        lj_pack8_kernel<<<ablocks, threads, 0, stream>>>(
            positions, species, tab8, cursor, nb, cap, N);
        const int athreads = 1024;
        const long nthreads_needed = ((long)P + 3) / 4;
        const int pblocksA = (int)((nthreads_needed + athreads - 1) / athreads);
        lj_passA_kernel<<<pblocksA, athreads, 0, stream>>>(
            tab8, cell, sigma_tab, eps_tab, shift_tab,
            pair_i, pair_j, shifts, record_buf, cursor, cap, nb, P);
        lj_passB_kernel<<<nb * SLICES, threads, 0, stream>>>(record_buf, cursor, partial, cap);
        lj_reduce_kernel<<<ablocks, threads, 0, stream>>>(partial, energy, N);
    } else if (use_pack) {
        float4* packed = (float4*)d_ws;
        lj_zero_kernel<<<ablocks, threads, 0, stream>>>(energy, N);
        lj_pack_kernel<<<ablocks, threads, 0, stream>>>(positions, species, packed, N);
        lj_pairs_packed_kernel<<<pblocks4, threads, 0, stream>>>(
            packed, cell, sigma_tab, eps_tab, shift_tab,
            pair_i, pair_j, shifts, energy, P);
    } else {
        lj_zero_kernel<<<ablocks, threads, 0, stream>>>(energy, N);
        lj_pairs_kernel<<<pblocks4, threads, 0, stream>>>(
            positions, cell, sigma_tab, eps_tab, shift_tab, species,
            pair_i, pair_j, shifts, energy, P);
    }
}